// Round 11
// baseline (52.866 us; speedup 1.0000x reference)
//
#include <hip/hip_runtime.h>

// MesoLayer R10: R9 (reg-staged, 47.3us) deepened to a 3-reg-set rotation.
// Block = 256 threads = 256 rows, 16 chunks x 16 rows (1560 float4 flat).
// Phase k: FLUSH(k-1) -> ISSUE(chunk k+3 -> set k%3) -> COMPUTE(k) ->
//          WAITC(chunk k+1, exact) -> WRITE(set (k+1)%3 -> buf (k+1)&1) -> BAR.
// Sustained ~2 chunks (100 KB/CU) outstanding; loads fly ~2 phases before
// their ds_write consumes them -> memory pipe never starves during the
// compute/write tail (R9's per-phase issue hole).

static __device__ __forceinline__ float xsum(float a) {
  a += __shfl_xor(a, 16, 64);
  a += __shfl_xor(a, 32, 64);
  return a;
}
static __device__ __forceinline__ float xmax(float a) {
  a = fmaxf(a, __shfl_xor(a, 16, 64));
  a = fmaxf(a, __shfl_xor(a, 32, 64));
  return a;
}

// 64-lane segment (R5/R9-proven): lane (q=ln>>4, r=ln&15) covers row r,
// j in {q, q+4, ...}; shfl_xor 16/32 reduce; true max -> single-pass exp.
// Mt = upper-tri of M = W W^T.
template<int L, int SEGOFF, int OUTOFF>
__device__ __forceinline__ void seg64(const float* __restrict__ bp, int q,
                                      const float (&Mt)[15],
                                      float* __restrict__ ob) {
  constexpr int T[5][5] = {{0, 1, 2, 3, 4},  {1, 5, 6, 7, 8},
                           {2, 6, 9, 10, 11}, {3, 7, 10, 12, 13},
                           {4, 8, 11, 13, 14}};
  constexpr int NJ = (L + 3) / 4;
  const bool lastv = (q + 4 * (NJ - 1)) < L;

  float s[NJ][5];
#pragma unroll
  for (int k = 0; k < NJ; ++k) {
    int j = q + 4 * k;
    if (j > L - 1) j = L - 1;  // only last k can clamp
#pragma unroll
    for (int g = 0; g < 5; ++g) s[k][g] = bp[SEGOFF + j * 5 + g];
  }
#pragma unroll
  for (int g = 0; g < 5; ++g) s[NJ - 1][g] = lastv ? s[NJ - 1][g] : 0.f;

  float ssl[5];
#pragma unroll
  for (int g = 0; g < 5; ++g) {
    float a = s[0][g];
#pragma unroll
    for (int k = 1; k < NJ; ++k) a += s[k][g];
    ssl[g] = xsum(a);
  }

  float v[5];
#pragma unroll
  for (int g = 0; g < 5; ++g) {
    float a = Mt[T[g][0]] * ssl[0];
#pragma unroll
    for (int h = 1; h < 5; ++h) a += Mt[T[g][h]] * ssl[h];
    v[g] = a;
  }

  float sc[NJ];
#pragma unroll
  for (int k = 0; k < NJ; ++k) {
    float a = s[k][0] * v[0];
#pragma unroll
    for (int g = 1; g < 5; ++g) a += s[k][g] * v[g];
    sc[k] = a;
  }
  sc[NJ - 1] = lastv ? sc[NJ - 1] : -3.0e38f;

  float ml = sc[0];
#pragma unroll
  for (int k = 1; k < NJ; ++k) ml = fmaxf(ml, sc[k]);
  float m = xmax(ml);

  float d = 0.f, pl[5] = {0.f, 0.f, 0.f, 0.f, 0.f};
#pragma unroll
  for (int k = 0; k < NJ; ++k) {
    float e = __expf(sc[k] - m);  // masked k: exp(-huge)=0
    d += e;
#pragma unroll
    for (int g = 0; g < 5; ++g) pl[g] += e * s[k][g];
  }
  d = xsum(d);
  float inv = 1.0f / d;
#pragma unroll
  for (int g = 0; g < 5; ++g) pl[g] = xsum(pl[g]);
  if (q == 0) {
#pragma unroll
    for (int g = 0; g < 5; ++g) ob[OUTOFF + g] = pl[g] * inv;
  }
}

// LDS (float4): buf0 [0,1560) | buf1 [1560,3120) | outbuf [3120,3400)
// = 54.4 KB -> 2 blocks/CU.
__global__ __launch_bounds__(256, 2) void meso_kernel(
    const float* __restrict__ x, const float* __restrict__ w,
    float* __restrict__ out) {
  __shared__ __align__(16) float4 sm4[3400];
  float* smf = (float*)sm4;
  const int t = threadIdx.x;
  const int wv = t >> 6, ln = t & 63, q = ln >> 4, r = ln & 15;
  const size_t blk = blockIdx.x;
  const float4* xp4 = (const float4*)x + blk * 24960;  // 256*390/4
  float4* o4 = (float4*)out + blk * 2240;              // 256*35/4

  float4 A0, A1, A2, A3, A4, A5, A6 = make_float4(0, 0, 0, 0);
  float4 B0, B1, B2, B3, B4, B5, B6 = make_float4(0, 0, 0, 0);
  float4 C0, C1, C2, C3, C4, C5, C6 = make_float4(0, 0, 0, 0);

#define ISSUE(R, c)                                                    \
  { const float4* g_ = xp4 + (size_t)(c) * 1560;                       \
    R##0 = g_[t];        R##1 = g_[t + 256];  R##2 = g_[t + 512];      \
    R##3 = g_[t + 768];  R##4 = g_[t + 1024]; R##5 = g_[t + 1280];     \
    if (t >= 232) R##6 = g_[1304 + t]; }

#define WRITE(R, b)                                                    \
  { float4* l_ = sm4 + (b) * 1560;                                     \
    l_[t] = R##0;        l_[t + 256] = R##1;  l_[t + 512] = R##2;      \
    l_[t + 768] = R##3;  l_[t + 1024] = R##4; l_[t + 1280] = R##5;     \
    if (t >= 232) l_[1304 + t] = R##6; }

  // n = #VMEM ops this wave issued after the awaited chunk's last load
  // (wave3 carries the 24-lane tail -> 7 loads/chunk vs 6).
#define WAITC(n03, n3)                                                 \
  { if (wv == 3) asm volatile("s_waitcnt vmcnt(" #n3 ")" ::: "memory");\
    else         asm volatile("s_waitcnt vmcnt(" #n03 ")" ::: "memory"); }

#define BAR()                                                          \
  { asm volatile("s_waitcnt lgkmcnt(0)" ::: "memory");                 \
    __builtin_amdgcn_s_barrier();                                      \
    __builtin_amdgcn_sched_barrier(0); }

#define FLUSH(pp)                                                      \
  { if (ln < 35)                                                       \
      o4[(size_t)(pp) * 140 + wv * 35 + ln] =                          \
          sm4[3120 + ((pp) & 1) * 140 + wv * 35 + ln]; }

#define COMPUTE(par)                                                   \
  { const float* bp = smf + (par) * 6240 + r * 390;                    \
    float* ob = smf + 12480 + (par) * 560 + r * 35;                    \
    if (wv == 0) { seg64<25, 115, 15>(bp, q, Mt, ob); }                \
    else if (wv == 1) { seg64<12, 330, 30>(bp, q, Mt, ob);             \
                        seg64<5,  0,   0 >(bp, q, Mt, ob); }           \
    else if (wv == 2) { seg64<9,  25,  5 >(bp, q, Mt, ob);             \
                        seg64<9,  70,  10>(bp, q, Mt, ob); }           \
    else              { seg64<9,  240, 20>(bp, q, Mt, ob);             \
                        seg64<9,  285, 25>(bp, q, Mt, ob); } }

  // Phase k: FLUSH(k-1); ISSUE(chunk k+3 -> set k%3) [k<=12]; COMPUTE(k);
  // WAITC(chunk k+1); WRITE(set (k+1)%3 -> buf (k+1)&1) [k<=14]; BAR.
#define PHASE(k, Ri, Rw, n03, n3)                                      \
  {                                                                    \
    if ((k) > 0) FLUSH((k) - 1)                                        \
    if ((k) <= 12) ISSUE(Ri, (k) + 3)                                  \
    __builtin_amdgcn_sched_barrier(0);                                 \
    COMPUTE((k) & 1)                                                   \
    WAITC(n03, n3)                                                     \
    WRITE(Rw, ((k) + 1) & 1)                                           \
    BAR()                                                              \
  }

  ISSUE(A, 0)
  ISSUE(B, 1)
  ISSUE(C, 2)

  // Mt = upper-tri(W W^T), uniform scalar loads under the load shadow.
  float Mt[15];
  {
    int i = 0;
#pragma unroll
    for (int g = 0; g < 5; ++g)
#pragma unroll
      for (int h = g; h < 5; ++h, ++i) {
        float a = 0.f;
#pragma unroll
        for (int k = 0; k < 10; ++k) a += w[g * 10 + k] * w[h * 10 + k];
        Mt[i] = a;
      }
  }

  WAITC(12, 14)  // chunk 0 complete (newer = chunks 1,2)
  WRITE(A, 0)
  BAR()

  // Audited WAITC immediates (wv0-2 / wv3):
  // k=0: newer = C(2)@pro 6/7 + A(3)@k0 6/7            -> 12/14
  // k=1: newer = A(3)@k0 6/7 + st + B(4)@k1 6/7        -> 13/15
  // k=2..12: 2 stores + 2 issues                        -> 14/16
  // k=13: st + C(15)@k12 6/7 + st                       -> 8/9
  // k=14: 2 stores                                      -> 2/2
  PHASE(0,  A, B, 12, 14)
  PHASE(1,  B, C, 13, 15)
  PHASE(2,  C, A, 14, 16)
  PHASE(3,  A, B, 14, 16)
  PHASE(4,  B, C, 14, 16)
  PHASE(5,  C, A, 14, 16)
  PHASE(6,  A, B, 14, 16)
  PHASE(7,  B, C, 14, 16)
  PHASE(8,  C, A, 14, 16)
  PHASE(9,  A, B, 14, 16)
  PHASE(10, B, C, 14, 16)
  PHASE(11, C, A, 14, 16)
  PHASE(12, A, B, 14, 16)
  PHASE(13, B, C, 8,  9)
  PHASE(14, C, A, 2,  2)

  // Phase 15: no issue/write remain.
  FLUSH(14)
  COMPUTE(1)
  asm volatile("s_waitcnt lgkmcnt(0)" ::: "memory");
  __builtin_amdgcn_s_barrier();
  FLUSH(15)
}

extern "C" void kernel_launch(void* const* d_in, const int* in_sizes, int n_in,
                              void* d_out, int out_size, void* d_ws, size_t ws_size,
                              hipStream_t stream) {
  const float* x = (const float*)d_in[0];
  const float* w = (const float*)d_in[1];
  float* out = (float*)d_out;
  int B = in_sizes[0] / 390;  // 131072
  int grid = B / 256;         // 512 blocks = 2/CU, all resident
  meso_kernel<<<grid, 256, 0, stream>>>(x, w, out);
}

// Round 12
// 48.569 us; speedup vs baseline: 1.0885x; 1.0885x over previous
//
#include <hip/hip_runtime.h>

// MesoLayer R11: R9's reg-staged skeleton (47.3us best) + 3 LDS buffers with
// WRITE-before-COMPUTE -> sustained 2-chunk in-flight depth, 2 reg sets only.
// Block = 256 threads = 256 rows, 16 chunks x 16 rows (1560 float4 flat).
// Phase p: FLUSH(p-1) -> WAITC(chunk p+1; landed ~2 phases ago, free) ->
//   WRITE(set -> buf (p+1)%3) -> ISSUE(chunk p+3 into same set) ->
//   COMPUTE(p, buf p%3) -> BAR.
// Chunks p+2 AND p+3 stay in flight through compute and across the barrier:
// ~100 KB/CU outstanding sustained, issue event every phase -> no memory
// duty-cycle hole (R9's limiter). Rolled period-2 loop keeps code R9-sized
// (R10's 17x unroll bloat was the suspected regression cause).

static __device__ __forceinline__ float xsum(float a) {
  a += __shfl_xor(a, 16, 64);
  a += __shfl_xor(a, 32, 64);
  return a;
}
static __device__ __forceinline__ float xmax(float a) {
  a = fmaxf(a, __shfl_xor(a, 16, 64));
  a = fmaxf(a, __shfl_xor(a, 32, 64));
  return a;
}

// 64-lane segment (R5/R9-proven): lane (q=ln>>4, r=ln&15) covers row r,
// j in {q, q+4, ...}; shfl_xor 16/32 reduce; true max -> single-pass exp.
// Mt = upper-tri of M = W W^T.
template<int L, int SEGOFF, int OUTOFF>
__device__ __forceinline__ void seg64(const float* __restrict__ bp, int q,
                                      const float (&Mt)[15],
                                      float* __restrict__ ob) {
  constexpr int T[5][5] = {{0, 1, 2, 3, 4},  {1, 5, 6, 7, 8},
                           {2, 6, 9, 10, 11}, {3, 7, 10, 12, 13},
                           {4, 8, 11, 13, 14}};
  constexpr int NJ = (L + 3) / 4;
  const bool lastv = (q + 4 * (NJ - 1)) < L;

  float s[NJ][5];
#pragma unroll
  for (int k = 0; k < NJ; ++k) {
    int j = q + 4 * k;
    if (j > L - 1) j = L - 1;  // only last k can clamp
#pragma unroll
    for (int g = 0; g < 5; ++g) s[k][g] = bp[SEGOFF + j * 5 + g];
  }
#pragma unroll
  for (int g = 0; g < 5; ++g) s[NJ - 1][g] = lastv ? s[NJ - 1][g] : 0.f;

  float ssl[5];
#pragma unroll
  for (int g = 0; g < 5; ++g) {
    float a = s[0][g];
#pragma unroll
    for (int k = 1; k < NJ; ++k) a += s[k][g];
    ssl[g] = xsum(a);
  }

  float v[5];
#pragma unroll
  for (int g = 0; g < 5; ++g) {
    float a = Mt[T[g][0]] * ssl[0];
#pragma unroll
    for (int h = 1; h < 5; ++h) a += Mt[T[g][h]] * ssl[h];
    v[g] = a;
  }

  float sc[NJ];
#pragma unroll
  for (int k = 0; k < NJ; ++k) {
    float a = s[k][0] * v[0];
#pragma unroll
    for (int g = 1; g < 5; ++g) a += s[k][g] * v[g];
    sc[k] = a;
  }
  sc[NJ - 1] = lastv ? sc[NJ - 1] : -3.0e38f;

  float ml = sc[0];
#pragma unroll
  for (int k = 1; k < NJ; ++k) ml = fmaxf(ml, sc[k]);
  float m = xmax(ml);

  float d = 0.f, pl[5] = {0.f, 0.f, 0.f, 0.f, 0.f};
#pragma unroll
  for (int k = 0; k < NJ; ++k) {
    float e = __expf(sc[k] - m);  // masked k: exp(-huge)=0
    d += e;
#pragma unroll
    for (int g = 0; g < 5; ++g) pl[g] += e * s[k][g];
  }
  d = xsum(d);
  float inv = 1.0f / d;
#pragma unroll
  for (int g = 0; g < 5; ++g) pl[g] = xsum(pl[g]);
  if (q == 0) {
#pragma unroll
    for (int g = 0; g < 5; ++g) ob[OUTOFF + g] = pl[g] * inv;
  }
}

// LDS (floats): buf0 @0 | buf1 @6240 | buf2 @12480 (1560 fl4 each) |
// outbuf @18720 (2 x 560). Total 79360 B -> 2 blocks/CU.
__global__ __launch_bounds__(256, 2) void meso_kernel(
    const float* __restrict__ x, const float* __restrict__ w,
    float* __restrict__ out) {
  __shared__ __align__(16) float smf[19840];
  float4* sm4 = (float4*)smf;
  const int t = threadIdx.x;
  const int wv = t >> 6, ln = t & 63, q = ln >> 4, r = ln & 15;
  const size_t blk = blockIdx.x;
  const float4* xp4 = (const float4*)x + blk * 24960;  // 256*390/4
  float4* o4 = (float4*)out + blk * 2240;              // 256*35/4

  float4 A0, A1, A2, A3, A4, A5, A6 = make_float4(0, 0, 0, 0);
  float4 B0, B1, B2, B3, B4, B5, B6 = make_float4(0, 0, 0, 0);

#define ISSUE(R, c)                                                    \
  { const float4* g_ = xp4 + (size_t)(c) * 1560;                       \
    R##0 = g_[t];        R##1 = g_[t + 256];  R##2 = g_[t + 512];      \
    R##3 = g_[t + 768];  R##4 = g_[t + 1024]; R##5 = g_[t + 1280];     \
    if (t >= 232) R##6 = g_[1304 + t]; }

#define WRITE(R, bi)                                                   \
  { float4* l_ = sm4 + (bi) * 1560;                                    \
    l_[t] = R##0;        l_[t + 256] = R##1;  l_[t + 512] = R##2;      \
    l_[t + 768] = R##3;  l_[t + 1024] = R##4; l_[t + 1280] = R##5;     \
    if (t >= 232) l_[1304 + t] = R##6; }

  // n = #VMEM ops this wave issued after the awaited chunk's last load
  // (wave3 carries the 24-lane tail -> 7 loads/chunk vs 6).
#define WAITC(n03, n3)                                                 \
  { if (wv == 3) asm volatile("s_waitcnt vmcnt(" #n3 ")" ::: "memory");\
    else         asm volatile("s_waitcnt vmcnt(" #n03 ")" ::: "memory"); }

#define BAR()                                                          \
  { asm volatile("s_waitcnt lgkmcnt(0)" ::: "memory");                 \
    __builtin_amdgcn_s_barrier(); }

#define FLUSH(pp)                                                      \
  { if (ln < 35)                                                       \
      o4[(size_t)(pp) * 140 + wv * 35 + ln] =                          \
          sm4[4680 + ((pp) & 1) * 140 + wv * 35 + ln]; }

#define COMPUTE(cb, outp)                                              \
  { const float* bp = smf + (cb) * 6240 + r * 390;                     \
    float* ob = smf + 18720 + (outp) * 560 + r * 35;                   \
    if (wv == 0) { seg64<25, 115, 15>(bp, q, Mt, ob); }                \
    else if (wv == 1) { seg64<12, 330, 30>(bp, q, Mt, ob);             \
                        seg64<5,  0,   0 >(bp, q, Mt, ob); }           \
    else if (wv == 2) { seg64<9,  25,  5 >(bp, q, Mt, ob);             \
                        seg64<9,  70,  10>(bp, q, Mt, ob); }           \
    else              { seg64<9,  240, 20>(bp, q, Mt, ob);             \
                        seg64<9,  285, 25>(bp, q, Mt, ob); } }

  ISSUE(A, 0)
  ISSUE(B, 1)

  // Mt = upper-tri(W W^T): uniform addr -> scalar (SMEM/lgkm) loads, so the
  // vmcnt audit is untouched (verified by R5/R9 correctness).
  float Mt[15];
  {
    int i = 0;
#pragma unroll
    for (int g = 0; g < 5; ++g)
#pragma unroll
      for (int h = g; h < 5; ++h, ++i) {
        float a = 0.f;
#pragma unroll
        for (int k = 0; k < 10; ++k) a += w[g * 10 + k] * w[h * 10 + k];
        Mt[i] = a;
      }
  }

  // Prologue: land chunk0 -> buf0, refill A with chunk2.
  WAITC(6, 7)        // chunk0 done (newer = chunk1's 6/7)
  WRITE(A, 0)
  ISSUE(A, 2)
  BAR()

  // Phase 0: chunk1 done (newer = ISSUE(A,2) 6/7).
  WAITC(6, 7)
  WRITE(B, 1)
  ISSUE(B, 3)
  COMPUTE(0, 0)
  BAR()

  // Phase 1: chunk2 done (newer = ISSUE(B,3) 6/7 + FLUSH st 1).
  FLUSH(0)
  WAITC(7, 8)
  WRITE(A, 2)
  ISSUE(A, 4)
  COMPUTE(1, 1)
  BAR()

  // Phases 2..13, rolled period-2. Entering iteration with base p:
  //   buf(p%3) holds chunk p; chunks p+1 (landed), p+2 in flight.
  // Steady WAITC = 8/9: newer than chunk p+1's last load (issued @p-2) are
  //   FLUSH st(@p-1) + ISSUE(@p-1) 6/7 + FLUSH st(@p).
  int cbE = 2;  // p % 3 at loop entry (p=2)
#pragma unroll 1
  for (int p = 2; p < 14; p += 2) {
    int wbE = cbE + 1; if (wbE >= 3) wbE -= 3;  // (p+1)%3
    int wbO = cbE + 2; if (wbO >= 3) wbO -= 3;  // (p+2)%3

    // even phase p
    FLUSH(p - 1)
    WAITC(8, 9)
    WRITE(B, wbE)
    if (p + 3 < 16) ISSUE(B, p + 3)
    COMPUTE(cbE, 0)
    BAR()

    // odd phase p+1
    FLUSH(p)
    WAITC(8, 9)
    WRITE(A, wbO)
    if (p + 4 < 16) ISSUE(A, p + 4)
    COMPUTE(wbE, 1)
    BAR()

    cbE = wbO;  // (p+2)%3
  }

  // Phase 14: chunk15 done (issued @ph12; newer = FLUSH st@13 + st@14 = 2).
  FLUSH(13)
  WAITC(2, 2)
  WRITE(B, 0)          // chunk15 -> buf 15%3 = 0
  COMPUTE(2, 0)        // chunk14 from buf 14%3 = 2
  BAR()

  // Phase 15: last compute, then final flushes.
  FLUSH(14)
  COMPUTE(0, 1)
  BAR()
  FLUSH(15)
}

extern "C" void kernel_launch(void* const* d_in, const int* in_sizes, int n_in,
                              void* d_out, int out_size, void* d_ws, size_t ws_size,
                              hipStream_t stream) {
  const float* x = (const float*)d_in[0];
  const float* w = (const float*)d_in[1];
  float* out = (float*)d_out;
  int B = in_sizes[0] / 390;  // 131072
  int grid = B / 256;         // 512 blocks = 2/CU, all resident
  meso_kernel<<<grid, 256, 0, stream>>>(x, w, out);
}

// Round 13
// 47.761 us; speedup vs baseline: 1.1069x; 1.0169x over previous
//
#include <hip/hip_runtime.h>

// MesoLayer R12: R9's skeleton (best, 47.3us) with ONE change: reduction
// lane-mapping moved to low lane bits (q = ln&3, r = ln>>2) so all
// cross-lane reduces are __shfl_xor 1/2 -> DPP quad_perm on the VALU pipe
// (R9/R11's xor 16/32 -> ds_bpermute: LDS pipe, ~60cy latency, chained 8+
// deep = the ~0.9us/phase residual R11's depth experiment exonerated memory
// from).
// Block = 256 threads = 256 rows, 16 chunks x 16 rows (1560 float4 flat).
// Phase p: FLUSH(p-1) -> ISSUE(chunk p+2) -> COMPUTE(p) -> WAITC(chunk p+1)
// -> WRITE -> lgkm0+barrier.

static __device__ __forceinline__ float xsum(float a) {
  a += __shfl_xor(a, 1, 64);   // quad_perm DPP
  a += __shfl_xor(a, 2, 64);   // quad_perm DPP
  return a;
}
static __device__ __forceinline__ float xmax(float a) {
  a = fmaxf(a, __shfl_xor(a, 1, 64));
  a = fmaxf(a, __shfl_xor(a, 2, 64));
  return a;
}

// 64-lane segment: lane (q=ln&3, r=ln>>2) covers row r, j in {q, q+4, ...};
// reduce over q via DPP quad_perm; true global max -> single-pass exp.
// Mt = upper-tri of M = W W^T. LDS bank check: addr%32=(6r+5q+c)%32 ->
// worst-case 2-way aliasing (free, m136).
template<int L, int SEGOFF, int OUTOFF>
__device__ __forceinline__ void seg64(const float* __restrict__ bp, int q,
                                      const float (&Mt)[15],
                                      float* __restrict__ ob) {
  constexpr int T[5][5] = {{0, 1, 2, 3, 4},  {1, 5, 6, 7, 8},
                           {2, 6, 9, 10, 11}, {3, 7, 10, 12, 13},
                           {4, 8, 11, 13, 14}};
  constexpr int NJ = (L + 3) / 4;
  const bool lastv = (q + 4 * (NJ - 1)) < L;

  float s[NJ][5];
#pragma unroll
  for (int k = 0; k < NJ; ++k) {
    int j = q + 4 * k;
    if (j > L - 1) j = L - 1;  // only last k can clamp
#pragma unroll
    for (int g = 0; g < 5; ++g) s[k][g] = bp[SEGOFF + j * 5 + g];
  }
#pragma unroll
  for (int g = 0; g < 5; ++g) s[NJ - 1][g] = lastv ? s[NJ - 1][g] : 0.f;

  float ssl[5];
#pragma unroll
  for (int g = 0; g < 5; ++g) {
    float a = s[0][g];
#pragma unroll
    for (int k = 1; k < NJ; ++k) a += s[k][g];
    ssl[g] = xsum(a);  // full subsum on all lanes
  }

  float v[5];
#pragma unroll
  for (int g = 0; g < 5; ++g) {
    float a = Mt[T[g][0]] * ssl[0];
#pragma unroll
    for (int h = 1; h < 5; ++h) a += Mt[T[g][h]] * ssl[h];
    v[g] = a;
  }

  float sc[NJ];
#pragma unroll
  for (int k = 0; k < NJ; ++k) {
    float a = s[k][0] * v[0];
#pragma unroll
    for (int g = 1; g < 5; ++g) a += s[k][g] * v[g];
    sc[k] = a;
  }
  sc[NJ - 1] = lastv ? sc[NJ - 1] : -3.0e38f;

  float ml = sc[0];
#pragma unroll
  for (int k = 1; k < NJ; ++k) ml = fmaxf(ml, sc[k]);
  float m = xmax(ml);

  float d = 0.f, pl[5] = {0.f, 0.f, 0.f, 0.f, 0.f};
#pragma unroll
  for (int k = 0; k < NJ; ++k) {
    float e = __expf(sc[k] - m);  // masked k: exp(-huge)=0
    d += e;
#pragma unroll
    for (int g = 0; g < 5; ++g) pl[g] += e * s[k][g];
  }
  d = xsum(d);
  float inv = 1.0f / d;
#pragma unroll
  for (int g = 0; g < 5; ++g) pl[g] = xsum(pl[g]);
  if (q == 0) {
#pragma unroll
    for (int g = 0; g < 5; ++g) ob[OUTOFF + g] = pl[g] * inv;
  }
}

// LDS (float4 units): buf0 [0,1560) | buf1 [1560,3120) | outbuf [3120,3400)
// = 54.4 KB -> 2 blocks/CU (grid is 2/CU anyway).
__global__ __launch_bounds__(256, 2) void meso_kernel(
    const float* __restrict__ x, const float* __restrict__ w,
    float* __restrict__ out) {
  __shared__ __align__(16) float4 sm4[3400];
  float* smf = (float*)sm4;
  const int t = threadIdx.x;
  const int wv = t >> 6, ln = t & 63, q = ln & 3, r = ln >> 2;
  const size_t blk = blockIdx.x;
  const float4* xp4 = (const float4*)x + blk * 24960;  // 256*390/4
  float4* o4 = (float4*)out + blk * 2240;              // 256*35/4

  float4 A0, A1, A2, A3, A4, A5, A6 = make_float4(0, 0, 0, 0);
  float4 B0, B1, B2, B3, B4, B5, B6 = make_float4(0, 0, 0, 0);

  // Stage-issue chunk c into reg set (6 full loads + wave3 tail of 24).
#define ISSUE(R, c)                                                    \
  { const float4* g_ = xp4 + (size_t)(c) * 1560;                       \
    R##0 = g_[t];        R##1 = g_[t + 256];  R##2 = g_[t + 512];      \
    R##3 = g_[t + 768];  R##4 = g_[t + 1024]; R##5 = g_[t + 1280];     \
    if (t >= 232) R##6 = g_[1304 + t]; }

#define WRITE(R, b)                                                    \
  { float4* l_ = sm4 + (b) * 1560;                                     \
    l_[t] = R##0;        l_[t + 256] = R##1;  l_[t + 512] = R##2;      \
    l_[t + 768] = R##3;  l_[t + 1024] = R##4; l_[t + 1280] = R##5;     \
    if (t >= 232) l_[1304 + t] = R##6; }

  // n = #VMEM ops this wave issued after the awaited chunk's last load
  // (wave3 carries the 24-lane tail -> 7 loads/chunk vs 6).
#define WAITC(n03, n3)                                                 \
  { if (wv == 3) asm volatile("s_waitcnt vmcnt(" #n3 ")" ::: "memory");\
    else         asm volatile("s_waitcnt vmcnt(" #n03 ")" ::: "memory"); }

#define BAR()                                                          \
  { asm volatile("s_waitcnt lgkmcnt(0)" ::: "memory");                 \
    __builtin_amdgcn_s_barrier();                                      \
    __builtin_amdgcn_sched_barrier(0); }

#define FLUSH(pp)                                                      \
  { if (ln < 35)                                                       \
      o4[(size_t)(pp) * 140 + wv * 35 + ln] =                          \
          sm4[3120 + ((pp) & 1) * 140 + wv * 35 + ln]; }

#define COMPUTE(par)                                                   \
  { const float* bp = smf + (par) * 6240 + r * 390;                    \
    float* ob = smf + 12480 + (par) * 560 + r * 35;                    \
    if (wv == 0) { seg64<25, 115, 15>(bp, q, Mt, ob); }                \
    else if (wv == 1) { seg64<12, 330, 30>(bp, q, Mt, ob);             \
                        seg64<5,  0,   0 >(bp, q, Mt, ob); }           \
    else if (wv == 2) { seg64<9,  25,  5 >(bp, q, Mt, ob);             \
                        seg64<9,  70,  10>(bp, q, Mt, ob); }           \
    else              { seg64<9,  240, 20>(bp, q, Mt, ob);             \
                        seg64<9,  285, 25>(bp, q, Mt, ob); } }

  ISSUE(A, 0)
  ISSUE(B, 1)

  // Mt = upper-tri(W W^T) from uniform scalar loads, overlapping load latency.
  float Mt[15];
  {
    int i = 0;
#pragma unroll
    for (int g = 0; g < 5; ++g)
#pragma unroll
      for (int h = g; h < 5; ++h, ++i) {
        float a = 0.f;
#pragma unroll
        for (int k = 0; k < 10; ++k) a += w[g * 10 + k] * w[h * 10 + k];
        Mt[i] = a;
      }
  }

  WAITC(6, 7)      // chunk0 complete (newer = chunk1's 6/7 loads)
  WRITE(A, 0)
  BAR()

#pragma unroll 1
  for (int p = 0; p < 16; p += 2) {
    // ---- even phase p: compute buf0/out0; B holds chunk p+1 ----
    if (p > 0) FLUSH(p - 1)
    if (p + 2 < 16) ISSUE(A, p + 2)
    COMPUTE(0)
    if (p == 0)       WAITC(6, 7)   // newer = issue(p+2) only
    else if (p < 14)  WAITC(7, 8)   // newer = flush store + issue(p+2)
    else              WAITC(1, 1)   // p=14: newer = flush store only
    WRITE(B, 1)
    BAR()

    // ---- odd phase p+1: compute buf1/out1; A holds chunk p+2 ----
    FLUSH(p)
    if (p + 3 < 16) ISSUE(B, p + 3)
    COMPUTE(1)
    if (p + 2 < 16) {
      if (p + 1 < 14) WAITC(7, 8)
      else            WAITC(1, 1)
      WRITE(A, 0)
    }
    BAR()
  }
  FLUSH(15)
}

extern "C" void kernel_launch(void* const* d_in, const int* in_sizes, int n_in,
                              void* d_out, int out_size, void* d_ws, size_t ws_size,
                              hipStream_t stream) {
  const float* x = (const float*)d_in[0];
  const float* w = (const float*)d_in[1];
  float* out = (float*)d_out;
  int B = in_sizes[0] / 390;  // 131072
  int grid = B / 256;         // 512 blocks = 2/CU, all resident
  meso_kernel<<<grid, 256, 0, stream>>>(x, w, out);
}